// Round 1
// baseline (220.782 us; speedup 1.0000x reference)
//
#include <hip/hip_runtime.h>

typedef unsigned short u16;
typedef unsigned int u32;
typedef __attribute__((ext_vector_type(8))) short short8;
typedef __attribute__((ext_vector_type(4))) float f32x4;

#define AS1 __attribute__((address_space(1)))
#define AS3 __attribute__((address_space(3)))

__device__ __forceinline__ u16 f2bf(float f) {
  u32 u = __float_as_uint(f);
  u32 r = u + 0x7FFFu + ((u >> 16) & 1u);
  return (u16)(r >> 16);
}
__device__ __forceinline__ float bf2f(u16 b) {
  return __uint_as_float(((u32)b) << 16);
}

__device__ __forceinline__ void gload_lds16(const void* g, void* l) {
  __builtin_amdgcn_global_load_lds((const AS1 u32*)g, (AS3 u32*)l, 16, 0, 0);
}

__device__ __forceinline__ f32x4 mfma16(short8 a, short8 b, f32x4 c) {
  return __builtin_amdgcn_mfma_f32_16x16x32_bf16(a, b, c, 0, 0, 0);
}

// ---------------- prep kernels ----------------

// fp32 [1024][1024] -> bf16 transposed [o][i]
__global__ void transpose_cvt(const float* __restrict__ W0, const float* __restrict__ W1,
                              const float* __restrict__ W2, const float* __restrict__ W3,
                              u16* __restrict__ T0, u16* __restrict__ T1,
                              u16* __restrict__ T2, u16* __restrict__ T3) {
  const float* W = blockIdx.z == 0 ? W0 : blockIdx.z == 1 ? W1 : blockIdx.z == 2 ? W2 : W3;
  u16* T = blockIdx.z == 0 ? T0 : blockIdx.z == 1 ? T1 : blockIdx.z == 2 ? T2 : T3;
  __shared__ float t[32][33];
  int bo = blockIdx.x * 32, bi = blockIdx.y * 32;
  int tx = threadIdx.x, ty = threadIdx.y;
#pragma unroll
  for (int k = 0; k < 4; ++k)
    t[ty + k * 8][tx] = W[(size_t)(bi + ty + k * 8) * 1024 + bo + tx];
  __syncthreads();
#pragma unroll
  for (int k = 0; k < 4; ++k)
    T[(size_t)(bo + ty + k * 8) * 1024 + bi + tx] = f2bf(t[tx][ty + k * 8]);
}

// fp32 -> bf16, 4 elems/thread
__global__ void cvt_bf16(const float* __restrict__ src, u16* __restrict__ dst) {
  int i = (blockIdx.x * 256 + threadIdx.x) * 4;
  float4 v = *(const float4*)(src + i);
  u32 lo = (u32)f2bf(v.x) | ((u32)f2bf(v.y) << 16);
  u32 hi = (u32)f2bf(v.z) | ((u32)f2bf(v.w) << 16);
  uint2 p; p.x = lo; p.y = hi;
  *(uint2*)(dst + i) = p;
}

// ---------------- GEMM: C[4096..][1024] = A[.][1024](bf16) * Bt[1024][1024](bf16)^T ----------------
// mode 0/1: out bf16 [B][H][S][DH]   (Q, K)
// mode 2:   out bf16 [B][H][DH][S]   (V^T)
// mode 3:   outf fp32 = acc + bias + resid   (pre-LN x)
__global__ __launch_bounds__(256)
void gemm_bt(const u16* __restrict__ A, const u16* __restrict__ Bt,
             const float* __restrict__ bias, const float* __restrict__ resid,
             u16* __restrict__ outb, float* __restrict__ outf, int mode) {
  const int K = 1024;
  __shared__ __align__(16) u16 As[128][32];
  __shared__ __align__(16) u16 Bs[128][32];
  int tid = threadIdx.x, wid = tid >> 6, lane = tid & 63;
  int wr = wid >> 1, wc = wid & 1;
  int brow = blockIdx.x * 128, bcol = blockIdx.y * 128;
  int fr = lane & 15, fq = lane >> 4, k0 = fq * 8;
  int srow = lane >> 2;       // staging: row within 16-row chunk
  int sk = (lane & 3) * 8;    // staging: k offset (elements)

  f32x4 acc[4][4];
#pragma unroll
  for (int m = 0; m < 4; ++m)
#pragma unroll
    for (int n = 0; n < 4; ++n) acc[m][n] = (f32x4){0.f, 0.f, 0.f, 0.f};

  for (int kt = 0; kt < K; kt += 32) {
#pragma unroll
    for (int c = 0; c < 2; ++c) {
      int chunk = wid * 2 + c;  // 0..7, each chunk = 16 rows x 32 k = 1KB
      gload_lds16(A + (size_t)(brow + chunk * 16 + srow) * K + kt + sk,
                  (char*)As + chunk * 1024);
      gload_lds16(Bt + (size_t)(bcol + chunk * 16 + srow) * K + kt + sk,
                  (char*)Bs + chunk * 1024);
    }
    __syncthreads();
    short8 afr[4], bfr[4];
#pragma unroll
    for (int m = 0; m < 4; ++m) afr[m] = *(const short8*)&As[wr * 64 + m * 16 + fr][k0];
#pragma unroll
    for (int n = 0; n < 4; ++n) bfr[n] = *(const short8*)&Bs[wc * 64 + n * 16 + fr][k0];
#pragma unroll
    for (int m = 0; m < 4; ++m)
#pragma unroll
      for (int n = 0; n < 4; ++n)
        acc[m][n] = mfma16(afr[m], bfr[n], acc[m][n]);
    __syncthreads();
  }

#pragma unroll
  for (int m = 0; m < 4; ++m)
#pragma unroll
    for (int n = 0; n < 4; ++n)
#pragma unroll
      for (int j = 0; j < 4; ++j) {
        int r = brow + wr * 64 + m * 16 + fq * 4 + j;  // t index
        int c = bcol + wc * 64 + n * 16 + fr;          // o index
        float v = acc[m][n][j] + bias[c];
        if (mode == 3) {
          v += resid[(size_t)r * 1024 + c];
          outf[(size_t)r * 1024 + c] = v;
        } else {
          int b = r >> 9, s = r & 511;
          int hh = c >> 6, d = c & 63;
          size_t o;
          if (mode != 2) o = (((size_t)(b * 16 + hh)) * 512 + s) * 64 + d;
          else           o = (((size_t)(b * 16 + hh)) * 64 + d) * 512 + s;
          outb[o] = f2bf(v);
        }
      }
}

// ---------------- fused attention ----------------
// grid (S/64, B*H), 256 thr. wave w handles q rows [qtile*64 + w*16, +16) x all 512 keys.
__global__ __launch_bounds__(256)
void attention(const u16* __restrict__ Q, const u16* __restrict__ K,
               const u16* __restrict__ Vt, const float* __restrict__ mask,
               float* __restrict__ score_out, u16* __restrict__ ctx) {
  const int S = 512, DH = 64;
  int bh = blockIdx.y;
  int b = bh >> 4, h = bh & 15;
  int tid = threadIdx.x;
  int wid = tid >> 6, lane = tid & 63;
  int fr = lane & 15, fq = lane >> 4, k0 = fq * 8;
  int qrow0 = blockIdx.x * 64 + wid * 16;

  const u16* Qp = Q + ((size_t)bh * S + qrow0) * DH;
  const u16* Kp = K + (size_t)bh * S * DH;
  const u16* Vp = Vt + (size_t)bh * DH * S;
  const float* mrow = mask + b * S;
  float* srow = score_out + ((size_t)bh * S + qrow0) * S;

  __shared__ __align__(16) u16 Pl[4][16][512];  // per-wave P chunk, XOR-swizzled

  // Q fragments (rows fr, k = ks*32 + k0)
  short8 af[2];
#pragma unroll
  for (int ks = 0; ks < 2; ++ks)
    af[ks] = *(const short8*)(Qp + (size_t)fr * DH + ks * 32 + k0);

  // scores: 32 col-fragments of 16
  f32x4 sacc[32];
#pragma unroll
  for (int nb = 0; nb < 32; ++nb) sacc[nb] = (f32x4){0.f, 0.f, 0.f, 0.f};
#pragma unroll
  for (int nb = 0; nb < 32; ++nb) {
#pragma unroll
    for (int ks = 0; ks < 2; ++ks) {
      short8 kf = *(const short8*)(Kp + (size_t)(nb * 16 + fr) * DH + ks * 32 + k0);
      sacc[nb] = mfma16(af[ks], kf, sacc[nb]);
    }
  }

  // scale + mask + emit raw scores + row max
  float rmax[4] = {-1e30f, -1e30f, -1e30f, -1e30f};
#pragma unroll
  for (int nb = 0; nb < 32; ++nb) {
    float mv = mrow[nb * 16 + fr] * (-10000.0f);
#pragma unroll
    for (int j = 0; j < 4; ++j) {
      float s = sacc[nb][j] * 0.125f + mv;
      sacc[nb][j] = s;
      srow[(size_t)(fq * 4 + j) * S + nb * 16 + fr] = s;
      rmax[j] = fmaxf(rmax[j], s);
    }
  }
#pragma unroll
  for (int j = 0; j < 4; ++j)
#pragma unroll
    for (int o = 1; o < 16; o <<= 1) rmax[j] = fmaxf(rmax[j], __shfl_xor(rmax[j], o, 64));

  // exp, row sum, write P (bf16, swizzled) to this wave's LDS chunk
  float rsum[4] = {0.f, 0.f, 0.f, 0.f};
#pragma unroll
  for (int nb = 0; nb < 32; ++nb) {
#pragma unroll
    for (int j = 0; j < 4; ++j) {
      float p = __expf(sacc[nb][j] - rmax[j]);
      rsum[j] += p;
      int row = fq * 4 + j;
      int col = nb * 16 + fr;
      Pl[wid][row][col ^ ((row & 7) << 3)] = f2bf(p);
    }
  }
#pragma unroll
  for (int j = 0; j < 4; ++j)
#pragma unroll
    for (int o = 1; o < 16; o <<= 1) rsum[j] += __shfl_xor(rsum[j], o, 64);

  // PV: ctx[16 q][64 d] = P[16][512] * V[512][64]  (V^T layout, B-frag k-contiguous)
  f32x4 cacc[4];
#pragma unroll
  for (int n = 0; n < 4; ++n) cacc[n] = (f32x4){0.f, 0.f, 0.f, 0.f};
#pragma unroll
  for (int ks = 0; ks < 16; ++ks) {
    int kk = ks * 32 + k0;
    short8 pa = *(const short8*)&Pl[wid][fr][kk ^ ((fr & 7) << 3)];
#pragma unroll
    for (int n = 0; n < 4; ++n) {
      short8 vf = *(const short8*)(Vp + (size_t)(n * 16 + fr) * S + kk);
      cacc[n] = mfma16(pa, vf, cacc[n]);
    }
  }

  // epilogue: divide by denom, store ctx bf16 [t][h*64+d]
#pragma unroll
  for (int n = 0; n < 4; ++n)
#pragma unroll
    for (int j = 0; j < 4; ++j) {
      float v = cacc[n][j] / rsum[j];
      int q = qrow0 + fq * 4 + j;
      int d = n * 16 + fr;
      ctx[((size_t)(b * 512 + q)) * 1024 + h * 64 + d] = f2bf(v);
    }
}

// ---------------- LayerNorm ----------------
__global__ __launch_bounds__(256)
void ln_kernel(const float* __restrict__ x, const float* __restrict__ g,
               const float* __restrict__ be, float* __restrict__ out) {
  int row = blockIdx.x, t = threadIdx.x;
  const float4* xr = (const float4*)(x + (size_t)row * 1024);
  float4 v = xr[t];
  float s = v.x + v.y + v.z + v.w;
  float s2 = v.x * v.x + v.y * v.y + v.z * v.z + v.w * v.w;
#pragma unroll
  for (int o = 1; o < 64; o <<= 1) {
    s += __shfl_xor(s, o, 64);
    s2 += __shfl_xor(s2, o, 64);
  }
  __shared__ float ls[4], ls2[4];
  int w = t >> 6;
  if ((t & 63) == 0) { ls[w] = s; ls2[w] = s2; }
  __syncthreads();
  float S = ls[0] + ls[1] + ls[2] + ls[3];
  float S2 = ls2[0] + ls2[1] + ls2[2] + ls2[3];
  float mu = S * (1.0f / 1024.0f);
  float var = S2 * (1.0f / 1024.0f) - mu * mu;
  float r = rsqrtf(var + 1e-5f);
  float4 gv = ((const float4*)g)[t];
  float4 bv = ((const float4*)be)[t];
  float4 o4;
  o4.x = gv.x * (v.x - mu) * r + bv.x;
  o4.y = gv.y * (v.y - mu) * r + bv.y;
  o4.z = gv.z * (v.z - mu) * r + bv.z;
  o4.w = gv.w * (v.w - mu) * r + bv.w;
  ((float4*)(out + (size_t)row * 1024))[t] = o4;
}

// ---------------- launch ----------------
extern "C" void kernel_launch(void* const* d_in, const int* in_sizes, int n_in,
                              void* d_out, int out_size, void* d_ws, size_t ws_size,
                              hipStream_t stream) {
  const float* hidden = (const float*)d_in[0];
  const float* mask   = (const float*)d_in[1];
  const float* Wq = (const float*)d_in[2];  const float* bq = (const float*)d_in[3];
  const float* Wk = (const float*)d_in[4];  const float* bk = (const float*)d_in[5];
  const float* Wv = (const float*)d_in[6];  const float* bv = (const float*)d_in[7];
  const float* Wo = (const float*)d_in[8];  const float* bo = (const float*)d_in[9];
  const float* gamma = (const float*)d_in[10];
  const float* beta  = (const float*)d_in[11];

  float* out = (float*)d_out;
  float* attn_out = out + 4194304;  // [B][H][S][S]

  char* ws = (char*)d_ws;
  u16* hbf = (u16*)(ws);                    // [4096][1024] bf16
  u16* WqT = (u16*)(ws + 8388608);          // [1024][1024] bf16 (transposed)
  u16* WkT = (u16*)(ws + 10485760);
  u16* WvT = (u16*)(ws + 12582912);
  u16* WoT = (u16*)(ws + 14680064);
  u16* Qb  = (u16*)(ws + 16777216);         // [B][H][S][DH]
  u16* Kb  = (u16*)(ws + 25165824);         // [B][H][S][DH]
  u16* Vt  = (u16*)(ws + 33554432);         // [B][H][DH][S]
  u16* ctx = (u16*)(ws + 41943040);         // [4096][1024]
  float* xres = (float*)(ws + 50331648);    // [4096][1024] fp32

  transpose_cvt<<<dim3(32, 32, 4), dim3(32, 8), 0, stream>>>(Wq, Wk, Wv, Wo, WqT, WkT, WvT, WoT);
  cvt_bf16<<<4096, 256, 0, stream>>>(hidden, hbf);
  gemm_bt<<<dim3(32, 8), 256, 0, stream>>>(hbf, WqT, bq, nullptr, Qb, nullptr, 0);
  gemm_bt<<<dim3(32, 8), 256, 0, stream>>>(hbf, WkT, bk, nullptr, Kb, nullptr, 1);
  gemm_bt<<<dim3(32, 8), 256, 0, stream>>>(hbf, WvT, bv, nullptr, Vt, nullptr, 2);
  attention<<<dim3(8, 128), 256, 0, stream>>>(Qb, Kb, Vt, mask, attn_out, ctx);
  gemm_bt<<<dim3(32, 8), 256, 0, stream>>>(ctx, WoT, bo, hidden, nullptr, xres, 3);
  ln_kernel<<<4096, 256, 0, stream>>>(xres, gamma, beta, out);
}

// Round 2
// 187.091 us; speedup vs baseline: 1.1801x; 1.1801x over previous
//
#include <hip/hip_runtime.h>

typedef unsigned short u16;
typedef unsigned int u32;
typedef __attribute__((ext_vector_type(8))) short short8;
typedef __attribute__((ext_vector_type(4))) float f32x4;

#define AS1 __attribute__((address_space(1)))
#define AS3 __attribute__((address_space(3)))

__device__ __forceinline__ u16 f2bf(float f) {
  u32 u = __float_as_uint(f);
  u32 r = u + 0x7FFFu + ((u >> 16) & 1u);
  return (u16)(r >> 16);
}
__device__ __forceinline__ float bf2f(u16 b) {
  return __uint_as_float(((u32)b) << 16);
}

__device__ __forceinline__ void gload_lds16(const void* g, void* l) {
  __builtin_amdgcn_global_load_lds((const AS1 u32*)g, (AS3 u32*)l, 16, 0, 0);
}

__device__ __forceinline__ f32x4 mfma16(short8 a, short8 b, f32x4 c) {
  return __builtin_amdgcn_mfma_f32_16x16x32_bf16(a, b, c, 0, 0, 0);
}

// ---------------- prep kernels ----------------

// fp32 [1024][1024] -> bf16 transposed [o][i]; T pointers select destination
// (Wq/Wk/Wv go into one fused [3072][1024] buffer via pointer offsets)
__global__ void transpose_cvt(const float* __restrict__ W0, const float* __restrict__ W1,
                              const float* __restrict__ W2, const float* __restrict__ W3,
                              u16* __restrict__ T0, u16* __restrict__ T1,
                              u16* __restrict__ T2, u16* __restrict__ T3) {
  const float* W = blockIdx.z == 0 ? W0 : blockIdx.z == 1 ? W1 : blockIdx.z == 2 ? W2 : W3;
  u16* T = blockIdx.z == 0 ? T0 : blockIdx.z == 1 ? T1 : blockIdx.z == 2 ? T2 : T3;
  __shared__ float t[32][33];
  int bo = blockIdx.x * 32, bi = blockIdx.y * 32;
  int tx = threadIdx.x, ty = threadIdx.y;
#pragma unroll
  for (int k = 0; k < 4; ++k)
    t[ty + k * 8][tx] = W[(size_t)(bi + ty + k * 8) * 1024 + bo + tx];
  __syncthreads();
#pragma unroll
  for (int k = 0; k < 4; ++k)
    T[(size_t)(bo + ty + k * 8) * 1024 + bi + tx] = f2bf(t[tx][ty + k * 8]);
}

// fp32 -> bf16, 4 elems/thread
__global__ void cvt_bf16(const float* __restrict__ src, u16* __restrict__ dst) {
  int i = (blockIdx.x * 256 + threadIdx.x) * 4;
  float4 v = *(const float4*)(src + i);
  u32 lo = (u32)f2bf(v.x) | ((u32)f2bf(v.y) << 16);
  u32 hi = (u32)f2bf(v.z) | ((u32)f2bf(v.w) << 16);
  uint2 p; p.x = lo; p.y = hi;
  *(uint2*)(dst + i) = p;
}

// ---------------- fused QKV GEMM ----------------
// C[4096][3072] = hbf[4096][1024] * WqkvT[3072][1024]^T, grid (32, 24)
// col region 0..1023 -> Q [B][H][S][DH], 1024.. -> K same, 2048.. -> V^T [B][H][DH][S]
__global__ __launch_bounds__(256)
void gemm_qkv(const u16* __restrict__ A, const u16* __restrict__ Bt,
              const float* __restrict__ bq, const float* __restrict__ bk,
              const float* __restrict__ bv,
              u16* __restrict__ Qb, u16* __restrict__ Kb, u16* __restrict__ Vt) {
  const int K = 1024;
  __shared__ __align__(16) u16 As[128][32];
  __shared__ __align__(16) u16 Bs[128][32];
  int tid = threadIdx.x, wid = tid >> 6, lane = tid & 63;
  int wr = wid >> 1, wc = wid & 1;
  int brow = blockIdx.x * 128, bcol = blockIdx.y * 128;
  int proj = bcol >> 10;           // 0=Q 1=K 2=V, uniform per block
  int fr = lane & 15, fq = lane >> 4, k0 = fq * 8;
  int srow = lane >> 2;
  int sk = (lane & 3) * 8;

  f32x4 acc[4][4];
#pragma unroll
  for (int m = 0; m < 4; ++m)
#pragma unroll
    for (int n = 0; n < 4; ++n) acc[m][n] = (f32x4){0.f, 0.f, 0.f, 0.f};

  for (int kt = 0; kt < K; kt += 32) {
#pragma unroll
    for (int c = 0; c < 2; ++c) {
      int chunk = wid * 2 + c;
      gload_lds16(A + (size_t)(brow + chunk * 16 + srow) * K + kt + sk,
                  (char*)As + chunk * 1024);
      gload_lds16(Bt + (size_t)(bcol + chunk * 16 + srow) * K + kt + sk,
                  (char*)Bs + chunk * 1024);
    }
    __syncthreads();
    short8 afr[4], bfr[4];
#pragma unroll
    for (int m = 0; m < 4; ++m) afr[m] = *(const short8*)&As[wr * 64 + m * 16 + fr][k0];
#pragma unroll
    for (int n = 0; n < 4; ++n) bfr[n] = *(const short8*)&Bs[wc * 64 + n * 16 + fr][k0];
#pragma unroll
    for (int m = 0; m < 4; ++m)
#pragma unroll
      for (int n = 0; n < 4; ++n)
        acc[m][n] = mfma16(afr[m], bfr[n], acc[m][n]);
    __syncthreads();
  }

  const float* bp = proj == 0 ? bq : proj == 1 ? bk : bv;
  u16* outp = proj == 0 ? Qb : proj == 1 ? Kb : Vt;
#pragma unroll
  for (int m = 0; m < 4; ++m)
#pragma unroll
    for (int n = 0; n < 4; ++n)
#pragma unroll
      for (int j = 0; j < 4; ++j) {
        int r = brow + wr * 64 + m * 16 + fq * 4 + j;   // token
        int c = bcol + wc * 64 + n * 16 + fr;           // fused out col
        int cc = c & 1023;
        float v = acc[m][n][j] + bp[cc];
        int b = r >> 9, s = r & 511;
        int hh = cc >> 6, d = cc & 63;
        size_t o;
        if (proj != 2) o = (((size_t)(b * 16 + hh)) * 512 + s) * 64 + d;
        else           o = (((size_t)(b * 16 + hh)) * 64 + d) * 512 + s;
        outp[o] = f2bf(v);
      }
}

// ---------------- out-proj GEMM: xres = ctx @ Wo^T + bo + hidden ----------------
__global__ __launch_bounds__(256)
void gemm_out(const u16* __restrict__ A, const u16* __restrict__ Bt,
              const float* __restrict__ bias, const float* __restrict__ resid,
              float* __restrict__ outf) {
  const int K = 1024;
  __shared__ __align__(16) u16 As[128][32];
  __shared__ __align__(16) u16 Bs[128][32];
  int tid = threadIdx.x, wid = tid >> 6, lane = tid & 63;
  int wr = wid >> 1, wc = wid & 1;
  int brow = blockIdx.x * 128, bcol = blockIdx.y * 128;
  int fr = lane & 15, fq = lane >> 4, k0 = fq * 8;
  int srow = lane >> 2;
  int sk = (lane & 3) * 8;

  f32x4 acc[4][4];
#pragma unroll
  for (int m = 0; m < 4; ++m)
#pragma unroll
    for (int n = 0; n < 4; ++n) acc[m][n] = (f32x4){0.f, 0.f, 0.f, 0.f};

  for (int kt = 0; kt < K; kt += 32) {
#pragma unroll
    for (int c = 0; c < 2; ++c) {
      int chunk = wid * 2 + c;
      gload_lds16(A + (size_t)(brow + chunk * 16 + srow) * K + kt + sk,
                  (char*)As + chunk * 1024);
      gload_lds16(Bt + (size_t)(bcol + chunk * 16 + srow) * K + kt + sk,
                  (char*)Bs + chunk * 1024);
    }
    __syncthreads();
    short8 afr[4], bfr[4];
#pragma unroll
    for (int m = 0; m < 4; ++m) afr[m] = *(const short8*)&As[wr * 64 + m * 16 + fr][k0];
#pragma unroll
    for (int n = 0; n < 4; ++n) bfr[n] = *(const short8*)&Bs[wc * 64 + n * 16 + fr][k0];
#pragma unroll
    for (int m = 0; m < 4; ++m)
#pragma unroll
      for (int n = 0; n < 4; ++n)
        acc[m][n] = mfma16(afr[m], bfr[n], acc[m][n]);
    __syncthreads();
  }

#pragma unroll
  for (int m = 0; m < 4; ++m)
#pragma unroll
    for (int n = 0; n < 4; ++n)
#pragma unroll
      for (int j = 0; j < 4; ++j) {
        int r = brow + wr * 64 + m * 16 + fq * 4 + j;
        int c = bcol + wc * 64 + n * 16 + fr;
        float v = acc[m][n][j] + bias[c] + resid[(size_t)r * 1024 + c];
        outf[(size_t)r * 1024 + c] = v;
      }
}

// ---------------- fused attention ----------------
// grid (S/64, B*H), 256 thr. wave w: q rows [qtile*64 + w*16, +16) x all 512 keys.
// Scores packed to bf16 pairs in regs (64 VGPR); PV in 128-key chunks through
// a double-buffered per-wave LDS tile (wave-local, no barriers).
__global__ __launch_bounds__(256, 4)
void attention(const u16* __restrict__ Q, const u16* __restrict__ K,
               const u16* __restrict__ Vt, const float* __restrict__ mask,
               float* __restrict__ score_out, u16* __restrict__ ctx) {
  const int S = 512, DH = 64;
  int bh = blockIdx.y;
  int b = bh >> 4, h = bh & 15;
  int tid = threadIdx.x;
  int wid = tid >> 6, lane = tid & 63;
  int fr = lane & 15, fq = lane >> 4, k0 = fq * 8;
  int qrow0 = blockIdx.x * 64 + wid * 16;

  const u16* Qp = Q + ((size_t)bh * S + qrow0) * DH;
  const u16* Kp = K + (size_t)bh * S * DH;
  const u16* Vp = Vt + (size_t)bh * DH * S;
  const float* mrow = mask + b * S;
  float* srow = score_out + ((size_t)bh * S + qrow0) * S;

  __shared__ __align__(16) u16 Pl[4][2][16][128];  // per-wave, double-buffered, swizzled

  // Q fragments (row fr, k = ks*32 + k0)
  short8 af0 = *(const short8*)(Qp + (size_t)fr * DH + k0);
  short8 af1 = *(const short8*)(Qp + (size_t)fr * DH + 32 + k0);

  // QK^T: per 16-col block compute, scale+mask, emit raw fp32 scores, pack bf16
  u32 pk[32][2];
  float rmax[4] = {-1e30f, -1e30f, -1e30f, -1e30f};
#pragma unroll
  for (int nb = 0; nb < 32; ++nb) {
    const u16* kp = Kp + (size_t)(nb * 16 + fr) * DH;
    short8 kf0 = *(const short8*)(kp + k0);
    short8 kf1 = *(const short8*)(kp + 32 + k0);
    f32x4 a = (f32x4){0.f, 0.f, 0.f, 0.f};
    a = mfma16(af0, kf0, a);
    a = mfma16(af1, kf1, a);
    float mv = mrow[nb * 16 + fr] * (-10000.0f);
    float s0 = a[0] * 0.125f + mv;
    float s1 = a[1] * 0.125f + mv;
    float s2 = a[2] * 0.125f + mv;
    float s3 = a[3] * 0.125f + mv;
    srow[(size_t)(fq * 4 + 0) * S + nb * 16 + fr] = s0;
    srow[(size_t)(fq * 4 + 1) * S + nb * 16 + fr] = s1;
    srow[(size_t)(fq * 4 + 2) * S + nb * 16 + fr] = s2;
    srow[(size_t)(fq * 4 + 3) * S + nb * 16 + fr] = s3;
    rmax[0] = fmaxf(rmax[0], s0);
    rmax[1] = fmaxf(rmax[1], s1);
    rmax[2] = fmaxf(rmax[2], s2);
    rmax[3] = fmaxf(rmax[3], s3);
    pk[nb][0] = (u32)f2bf(s0) | ((u32)f2bf(s1) << 16);
    pk[nb][1] = (u32)f2bf(s2) | ((u32)f2bf(s3) << 16);
  }
#pragma unroll
  for (int j = 0; j < 4; ++j)
#pragma unroll
    for (int o = 1; o < 16; o <<= 1) rmax[j] = fmaxf(rmax[j], __shfl_xor(rmax[j], o, 64));

  // exp + PV in 4 chunks of 128 keys, double-buffered wave-local LDS
  float rsum[4] = {0.f, 0.f, 0.f, 0.f};
  f32x4 cacc[4];
#pragma unroll
  for (int n = 0; n < 4; ++n) cacc[n] = (f32x4){0.f, 0.f, 0.f, 0.f};
#pragma unroll
  for (int ch = 0; ch < 4; ++ch) {
#pragma unroll
    for (int nb8 = 0; nb8 < 8; ++nb8) {
      int nb = ch * 8 + nb8;
      float sv[4];
      sv[0] = bf2f((u16)(pk[nb][0] & 0xffff));
      sv[1] = bf2f((u16)(pk[nb][0] >> 16));
      sv[2] = bf2f((u16)(pk[nb][1] & 0xffff));
      sv[3] = bf2f((u16)(pk[nb][1] >> 16));
#pragma unroll
      for (int j = 0; j < 4; ++j) {
        float p = __expf(sv[j] - rmax[j]);
        rsum[j] += p;
        int row = fq * 4 + j;
        int col = nb8 * 16 + fr;
        Pl[wid][ch & 1][row][col ^ ((row & 7) << 3)] = f2bf(p);
      }
    }
#pragma unroll
    for (int ks = 0; ks < 4; ++ks) {
      int kk = ks * 32 + k0;     // within chunk
      short8 pa = *(const short8*)&Pl[wid][ch & 1][fr][kk ^ ((fr & 7) << 3)];
      int kg = ch * 128 + kk;    // global key index
#pragma unroll
      for (int n = 0; n < 4; ++n) {
        short8 vf = *(const short8*)(Vp + (size_t)(n * 16 + fr) * S + kg);
        cacc[n] = mfma16(pa, vf, cacc[n]);
      }
    }
  }
#pragma unroll
  for (int j = 0; j < 4; ++j)
#pragma unroll
    for (int o = 1; o < 16; o <<= 1) rsum[j] += __shfl_xor(rsum[j], o, 64);

  // epilogue: divide by denom, store ctx bf16 [t][h*64+d]
#pragma unroll
  for (int n = 0; n < 4; ++n)
#pragma unroll
    for (int j = 0; j < 4; ++j) {
      float v = cacc[n][j] / rsum[j];
      int q = qrow0 + fq * 4 + j;
      int d = n * 16 + fr;
      ctx[((size_t)(b * 512 + q)) * 1024 + h * 64 + d] = f2bf(v);
    }
}

// ---------------- LayerNorm ----------------
__global__ __launch_bounds__(256)
void ln_kernel(const float* __restrict__ x, const float* __restrict__ g,
               const float* __restrict__ be, float* __restrict__ out) {
  int row = blockIdx.x, t = threadIdx.x;
  const float4* xr = (const float4*)(x + (size_t)row * 1024);
  float4 v = xr[t];
  float s = v.x + v.y + v.z + v.w;
  float s2 = v.x * v.x + v.y * v.y + v.z * v.z + v.w * v.w;
#pragma unroll
  for (int o = 1; o < 64; o <<= 1) {
    s += __shfl_xor(s, o, 64);
    s2 += __shfl_xor(s2, o, 64);
  }
  __shared__ float ls[4], ls2[4];
  int w = t >> 6;
  if ((t & 63) == 0) { ls[w] = s; ls2[w] = s2; }
  __syncthreads();
  float S = ls[0] + ls[1] + ls[2] + ls[3];
  float S2 = ls2[0] + ls2[1] + ls2[2] + ls2[3];
  float mu = S * (1.0f / 1024.0f);
  float var = S2 * (1.0f / 1024.0f) - mu * mu;
  float r = rsqrtf(var + 1e-5f);
  float4 gv = ((const float4*)g)[t];
  float4 bv = ((const float4*)be)[t];
  float4 o4;
  o4.x = gv.x * (v.x - mu) * r + bv.x;
  o4.y = gv.y * (v.y - mu) * r + bv.y;
  o4.z = gv.z * (v.z - mu) * r + bv.z;
  o4.w = gv.w * (v.w - mu) * r + bv.w;
  ((float4*)(out + (size_t)row * 1024))[t] = o4;
}

// ---------------- launch ----------------
extern "C" void kernel_launch(void* const* d_in, const int* in_sizes, int n_in,
                              void* d_out, int out_size, void* d_ws, size_t ws_size,
                              hipStream_t stream) {
  const float* hidden = (const float*)d_in[0];
  const float* mask   = (const float*)d_in[1];
  const float* Wq = (const float*)d_in[2];  const float* bq = (const float*)d_in[3];
  const float* Wk = (const float*)d_in[4];  const float* bk = (const float*)d_in[5];
  const float* Wv = (const float*)d_in[6];  const float* bv = (const float*)d_in[7];
  const float* Wo = (const float*)d_in[8];  const float* bo = (const float*)d_in[9];
  const float* gamma = (const float*)d_in[10];
  const float* beta  = (const float*)d_in[11];

  float* out = (float*)d_out;
  float* attn_out = out + 4194304;  // [B][H][S][S]

  char* ws = (char*)d_ws;
  u16* hbf    = (u16*)(ws);                 // [4096][1024] bf16
  u16* WqkvT  = (u16*)(ws + 8388608);       // [3072][1024] bf16 (Q,K,V transposed, fused)
  u16* WoT    = (u16*)(ws + 14680064);      // [1024][1024] bf16
  u16* Qb     = (u16*)(ws + 16777216);      // [B][H][S][DH]
  u16* Kb     = (u16*)(ws + 25165824);      // [B][H][S][DH]
  u16* Vt     = (u16*)(ws + 33554432);      // [B][H][DH][S]
  u16* ctx    = (u16*)(ws + 41943040);      // [4096][1024]
  float* xres = (float*)(ws + 50331648);    // [4096][1024] fp32

  transpose_cvt<<<dim3(32, 32, 4), dim3(32, 8), 0, stream>>>(
      Wq, Wk, Wv, Wo, WqkvT, WqkvT + 1048576, WqkvT + 2097152, WoT);
  cvt_bf16<<<4096, 256, 0, stream>>>(hidden, hbf);
  gemm_qkv<<<dim3(32, 24), 256, 0, stream>>>(hbf, WqkvT, bq, bk, bv, Qb, Kb, Vt);
  attention<<<dim3(8, 128), 256, 0, stream>>>(Qb, Kb, Vt, mask, attn_out, ctx);
  gemm_out<<<dim3(32, 8), 256, 0, stream>>>(ctx, WoT, bo, hidden, xres);
  ln_kernel<<<4096, 256, 0, stream>>>(xres, gamma, beta, out);
}